// Round 8
// baseline (902.872 us; speedup 1.0000x reference)
//
#include <hip/hip_runtime.h>

// Problem constants (fixed by setup_inputs)
static constexpr int V  = 5;
static constexpr int B  = 2;
static constexpr int C  = 32;
static constexpr int H  = 256;
static constexpr int W  = 320;
static constexpr int CN = 4;
static constexpr int HW = H * W;
static constexpr int CG = 8;   // channels per group (per wave)
static constexpr int NG = 4;   // groups per block
static constexpr int XT = W / 64;        // 5 x-tiles
static constexpr int NBLK = XT * H * B;  // 2560 fused blocks

static constexpr size_t PARAMS_OFF = 0;

typedef float f32x2 __attribute__((ext_vector_type(2)));
typedef float f32x4 __attribute__((ext_vector_type(4)));

// Alignment-safe paired load (global: dwordx2; LDS: ds_read2_b32)
__device__ __forceinline__ f32x2 ld2(const float* p) {
    f32x2 v;
    __builtin_memcpy(&v, p, sizeof(f32x2));
    return v;
}

// ---------------------------------------------------------------------------
// Setup: per (b, src view i=1..4) compute proj = M_i @ inv(M_0) -> 12 floats
// ---------------------------------------------------------------------------
__global__ void setup_proj_kernel(const float* __restrict__ pm, float* __restrict__ params) {
    int b = threadIdx.x;
    if (b >= B) return;

    float M[V][16];
    for (int v = 0; v < V; ++v) {
        const float* E  = pm + ((size_t)(b * V + v) * 2 + 0) * 16;
        const float* Km = pm + ((size_t)(b * V + v) * 2 + 1) * 16;
        for (int r = 0; r < 3; ++r)
            for (int c = 0; c < 4; ++c) {
                float s = 0.f;
                for (int k = 0; k < 3; ++k) s += Km[r * 4 + k] * E[k * 4 + c];
                M[v][r * 4 + c] = s;
            }
        for (int c = 0; c < 4; ++c) M[v][12 + c] = E[12 + c];
    }

    float A[9], bb[3];
    for (int r = 0; r < 3; ++r) {
        for (int c = 0; c < 3; ++c) A[r * 3 + c] = M[0][r * 4 + c];
        bb[r] = M[0][r * 4 + 3];
    }
    float det = A[0] * (A[4] * A[8] - A[5] * A[7])
              - A[1] * (A[3] * A[8] - A[5] * A[6])
              + A[2] * (A[3] * A[7] - A[4] * A[6]);
    float id = 1.f / det;
    float Ai[9];
    Ai[0] = (A[4] * A[8] - A[5] * A[7]) * id;
    Ai[1] = (A[2] * A[7] - A[1] * A[8]) * id;
    Ai[2] = (A[1] * A[5] - A[2] * A[4]) * id;
    Ai[3] = (A[5] * A[6] - A[3] * A[8]) * id;
    Ai[4] = (A[0] * A[8] - A[2] * A[6]) * id;
    Ai[5] = (A[2] * A[3] - A[0] * A[5]) * id;
    Ai[6] = (A[3] * A[7] - A[4] * A[6]) * id;
    Ai[7] = (A[1] * A[6] - A[0] * A[7]) * id;
    Ai[8] = (A[0] * A[4] - A[1] * A[3]) * id;
    float bi[3];
    for (int r = 0; r < 3; ++r)
        bi[r] = -(Ai[r * 3 + 0] * bb[0] + Ai[r * 3 + 1] * bb[1] + Ai[r * 3 + 2] * bb[2]);

    float Minv[16];
    for (int r = 0; r < 3; ++r) {
        for (int c = 0; c < 3; ++c) Minv[r * 4 + c] = Ai[r * 3 + c];
        Minv[r * 4 + 3] = bi[r];
    }
    Minv[12] = 0.f; Minv[13] = 0.f; Minv[14] = 0.f; Minv[15] = 1.f;

    for (int v = 1; v < V; ++v) {
        float* dst = params + (size_t)(b * (V - 1) + (v - 1)) * 12;
        for (int r = 0; r < 3; ++r)
            for (int c = 0; c < 4; ++c) {
                float s = 0.f;
                for (int k = 0; k < 4; ++k) s += M[v][r * 4 + k] * Minv[k * 4 + c];
                dst[r * 4 + c] = s;
            }
    }
}

// ---------------------------------------------------------------------------
// Fused kernel v8: minimal-register pipelined LDS row staging.
// Lesson of r3/r6/r7: every variant with VGPR<=64 runs ~143us; everything
// >=100 VGPR regresses via occupancy. So: r5's skeleton with
//  (1) 1 channel per phase, stage[NG][960] (15.6 KB LDS; 10 blocks/CU cap),
//  (2) register double-buffer R[4] (+16 VGPR): R holds ch n+1 while the
//      gather reads ch n from LDS -> global latency hides under the gather,
//  (3) FULLY unrolled 8-phase loop so rf[ch] is statically indexed
//      (r5's `unroll 1` + rf[cc] runtime index put rf in scratch, rule #20),
//  (4) no barriers in the loop: stage[g] is wave-private, same-wave DS ops
//      are in-order, so phase-to-phase WAR on the buffer is safe,
//  (5) paired ds_read2 gathers (4 values in 2 instrs),
//  (6) o0[] computed directly; fast test (unsigned)o0<=638; cold fallback
//      recomputes projection from scratch (no extra live arrays).
// __launch_bounds__(256,5) caps the allocator at ~102 VGPR as a guard.
// ---------------------------------------------------------------------------
__global__ __launch_bounds__(256, 5) void fused_kernel(
    const float* __restrict__ depth_values,   // (B,1,H,W)
    const float* __restrict__ features,       // (V,B,C,H,W)
    const float* __restrict__ depth_interval, // (B,1,H,W)
    const float* __restrict__ view_weights,   // (B,V-1,H,W)
    const float* __restrict__ params,         // (B,V-1,12)
    float* __restrict__ out)                  // (B,C*CN,H,W)
{
    const int tid = threadIdx.x;
    const int p   = tid & 63;
    const int g   = tid >> 6;

    // row-sharing XCD swizzle (bijective)
    const int d   = blockIdx.x;
    const int u   = d >> 3;             // 0..319
    const int r8  = d & 7;
    const int xt  = u % XT;
    const int rid = r8 * 64 + u / XT;   // 0..511
    const int y   = rid & (H - 1);
    const int b   = rid >> 8;

    const int x   = xt * 64 + p;
    const int pix = y * W + x;

    __shared__ float sp4[48];            // 4 views x 12 params
    __shared__ float stage[NG][960];     // per-group: 1ch x 3 rows x 320 (15.6 KB total)
    float* const sredp = &stage[0][0];   // aliased post-gather: [NG][CN][64]
    float* const simp  = &stage[0][0] + 1024;  // aliased post-gather: [CN][64]

    if (tid < 48) sp4[tid] = params[(size_t)b * 48 + tid];
    __syncthreads();

    const float invd = 1.f / depth_values[(size_t)b * HW + pix];
    const float itv  = depth_interval[(size_t)b * HW + pix];
    const float low  = invd - (CN * 0.5f) * itv;
    const float step = (CN * itv) / (float)(CN - 1);
    float dep[CN];
#pragma unroll
    for (int k = 0; k < CN; ++k) dep[k] = 1.f / (low + (float)k * step);

    // prefetch all 4 view weights (off the per-view critical chain)
    float vws[V - 1];
#pragma unroll
    for (int i = 0; i < V - 1; ++i)
        vws[i] = view_weights[((size_t)b * (V - 1) + i) * HW + pix];
    float wsum = 1e-5f;
#pragma unroll
    for (int i = 0; i < V - 1; ++i) wsum += vws[i];

    // this group's reference channels: read once -> NT load
    const float* refp = features + ((size_t)b * C + g * CG) * HW + pix;
    float rf[CG];
#pragma unroll
    for (int c = 0; c < CG; ++c) rf[c] = __builtin_nontemporal_load(refp + (size_t)c * HW);

    // per-lane staging offsets: slot = it*64+p covers 240 f32x4 = 960 floats
    // = 3 rows x 320 of ONE channel. Valid: slot<240 <=> it<3 || p<48.
    int soff[4];
#pragma unroll
    for (int it = 0; it < 4; ++it) {
        const int f   = (it * 64 + p) * 4;
        const int j   = (f >= 640) ? 2 : ((f >= 320) ? 1 : 0);
        const int col = f - j * 320;
        const int row = min(max(y - 1 + j, 0), H - 1);
        soff[it] = row * W + col;
    }

    // view iv source base for this group's channels; +VSTRIDE per view
    const size_t VSTRIDE = (size_t)B * C * HW;
    const float* src = features + ((size_t)(B + b) * C + g * CG) * HW;  // view 0 (iv=0)

    const float fx = (float)x, fy = (float)y;
    float volsum[CN] = {0.f, 0.f, 0.f, 0.f};

    // prime the register buffer with view0 ch0
    f32x4 R[4];
#pragma unroll
    for (int it = 0; it < 4; ++it)
        if (it < 3 || p < 48) R[it] = *(const f32x4*)(src + soff[it]);

    for (int iv = 0; iv < V - 1; ++iv, src += VSTRIDE) {
        const float* spv = &sp4[iv * 12];
        const float rx = spv[0] * fx + spv[1] * fy + spv[2];
        const float ry = spv[4] * fx + spv[5] * fy + spv[6];
        const float rz = spv[8] * fx + spv[9] * fy + spv[10];
        const float tx = spv[3], ty = spv[7], tz = spv[11];

        const float scale = vws[iv] * (1.f / (float)C);

        int   o0[CN];
        float wA0[CN], wB0[CN], wA1[CN], wB1[CN];
#pragma unroll
        for (int k = 0; k < CN; ++k) {
            const float dd = dep[k];
            const float px = rx * dd + tx;
            const float py = ry * dd + ty;
            const float pz = rz * dd + tz;
            const float iz = 1.f / pz;
            const float gx = px * iz;
            const float gy = py * iz;

            const float x0f = floorf(gx), y0f = floorf(gy);
            const float wx1 = gx - x0f, wy1 = gy - y0f;
            const float wx0 = 1.f - wx1, wy0 = 1.f - wy1;
            const int x0 = (int)x0f, y0 = (int)y0f;
            const int x1 = x0 + 1, y1 = y0 + 1;

            const bool vx0 = (x0 >= 0) && (x0 <= W - 1);
            const bool vx1 = (x1 >= 0) && (x1 <= W - 1);
            const bool vy0 = (y0 >= 0) && (y0 <= H - 1);
            const bool vy1 = (y1 >= 0) && (y1 <= H - 1);

            const int bx = min(max(x0, 0), W - 2);
            const int s  = x0 - bx;   // {-1, 0, 1} (else all weights 0)

            const float w00 = wx0 * wy0 * ((vx0 && vy0) ? scale : 0.f);
            const float w10 = wx1 * wy0 * ((vx1 && vy0) ? scale : 0.f);
            const float w01 = wx0 * wy1 * ((vx0 && vy1) ? scale : 0.f);
            const float w11 = wx1 * wy1 * ((vx1 && vy1) ? scale : 0.f);

            wA0[k] = (s == 0) ? w00 : ((s == -1) ? w10 : 0.f);
            wB0[k] = (s == 0) ? w10 : ((s == 1) ? w00 : 0.f);
            wA1[k] = (s == 0) ? w01 : ((s == -1) ? w11 : 0.f);
            wB1[k] = (s == 0) ? w11 : ((s == 1) ? w01 : 0.f);

            // staged-buffer offset; valid fast iff y0 in {y-1, y} <=> o0<=638
            o0[k] = (y0 - y + 1) * 320 + bx;
        }

        bool okrow = true;
#pragma unroll
        for (int k = 0; k < CN; ++k)
            okrow = okrow && ((unsigned)o0[k] <= 638u);

        if (__all(okrow)) {
            // 8 phases, fully unrolled (rf[ch] static). Per phase:
            // commit R (ch) -> LDS, prefetch ch+1 -> R, gather ch from LDS.
#pragma unroll
            for (int ch = 0; ch < CG; ++ch) {
                // commit staged regs (same-wave DS in-order: the previous
                // phase's ds_reads retire before these writes land)
#pragma unroll
                for (int it = 0; it < 4; ++it)
                    if (it < 3 || p < 48)
                        *(f32x4*)&stage[g][(it * 64 + p) * 4] = R[it];

                // issue-early prefetch of the next channel / next view's ch0
                const bool more = (ch < CG - 1) || (iv < V - 2);
                if (more) {
                    const float* nsrc = (ch < CG - 1) ? src + (size_t)(ch + 1) * HW
                                                      : src + VSTRIDE;
#pragma unroll
                    for (int it = 0; it < 4; ++it)
                        if (it < 3 || p < 48) R[it] = *(const f32x4*)(nsrc + soff[it]);
                }

                // gather this channel's 4 depths (paired ds_read2)
                const float rfc = rf[ch];
                const float* L = &stage[g][0];
#pragma unroll
                for (int k = 0; k < CN; ++k) {
                    const f32x2 a  = ld2(L + o0[k]);
                    const f32x2 b2 = ld2(L + o0[k] + 320);
                    float t = wA0[k] * a.x;
                    t = fmaf(wB0[k], a.y, t);
                    t = fmaf(wA1[k], b2.x, t);
                    t = fmaf(wB1[k], b2.y, t);
                    volsum[k] = fmaf(rfc, t, volsum[k]);
                }
            }
        } else {
            // GENERIC fallback (cold): compact global gather; recompute rows.
#pragma unroll 1
            for (int k = 0; k < CN; ++k) {
                const float dd = dep[k];
                const float gy = (ry * dd + ty) / (rz * dd + tz);
                const int   y0 = (int)floorf(gy);
                const int  cy0 = min(max(y0,     0), H - 1);
                const int  cy1 = min(max(y0 + 1, 0), H - 1);
                const int   bx = o0[k] - (y0 - y + 1) * 320;   // recover bx
                const int  ib0 = cy0 * W + bx;
                const int  ib1 = cy1 * W + bx;
#pragma unroll 1
                for (int c = 0; c < CG; ++c) {
                    const float* fc  = src + (size_t)c * HW;
                    const f32x2 a   = ld2(fc + ib0);
                    const f32x2 bb2 = ld2(fc + ib1);
                    float t = wA0[k] * a.x;
                    t = fmaf(wB0[k], a.y, t);
                    t = fmaf(wA1[k], bb2.x, t);
                    t = fmaf(wB1[k], bb2.y, t);
                    volsum[k] = fmaf(rf[c], t, volsum[k]);
                }
            }
            // re-prime the register buffer for the next view
            if (iv < V - 2) {
#pragma unroll
                for (int it = 0; it < 4; ++it)
                    if (it < 3 || p < 48) R[it] = *(const f32x4*)(src + VSTRIDE + soff[it]);
            }
        }
    }

    // cross-group reduce + normalize; sred/sim alias the (now dead) stage buf.
    __syncthreads();
#pragma unroll
    for (int k = 0; k < CN; ++k) sredp[(g * CN + k) * 64 + p] = volsum[k];
    __syncthreads();

    {
        const int k = g;   // NG == CN: group g owns depth k = g
        const float s = sredp[(0 * CN + k) * 64 + p] + sredp[(1 * CN + k) * 64 + p]
                      + sredp[(2 * CN + k) * 64 + p] + sredp[(3 * CN + k) * 64 + p];
        simp[k * 64 + p] = s * (1.f / wsum);
    }
    __syncthreads();

    // broadcast-write 128 planes x 64 px with regular cached stores.
    {
        const int quad = tid & 15;
        const int pc   = tid >> 4;
        float* op = out + (size_t)b * C * CN * HW + y * W + xt * 64 + quad * 4;
#pragma unroll
        for (int j = 0; j < 8; ++j) {
            const int plane = pc * 8 + j;          // 0..127, each exactly once
            const int k     = plane & 3;
            const f32x4 v   = *(const f32x4*)&simp[k * 64 + quad * 4];
            *(f32x4*)(op + (size_t)plane * HW) = v;
        }
    }
}

extern "C" void kernel_launch(void* const* d_in, const int* in_sizes, int n_in,
                              void* d_out, int out_size, void* d_ws, size_t ws_size,
                              hipStream_t stream) {
    const float* depth_values   = (const float*)d_in[0];
    const float* features       = (const float*)d_in[1];
    const float* proj_matrices  = (const float*)d_in[2];
    const float* depth_interval = (const float*)d_in[3];
    const float* view_weights   = (const float*)d_in[7];
    float* out    = (float*)d_out;
    float* params = (float*)d_ws + PARAMS_OFF;    // 96 floats

    setup_proj_kernel<<<1, B, 0, stream>>>(proj_matrices, params);

    fused_kernel<<<NBLK, 256, 0, stream>>>(depth_values, features, depth_interval,
                                           view_weights, params, out);
}

// Round 9
// 288.170 us; speedup vs baseline: 3.1331x; 3.1331x over previous
//
#include <hip/hip_runtime.h>

// Problem constants (fixed by setup_inputs)
static constexpr int V  = 5;
static constexpr int B  = 2;
static constexpr int C  = 32;
static constexpr int H  = 256;
static constexpr int W  = 320;
static constexpr int CN = 4;
static constexpr int HW = H * W;
static constexpr int CG = 8;   // channels per group (per wave)
static constexpr int NG = 4;   // groups per block
static constexpr int XT = W / 64;        // 5 x-tiles
static constexpr int NBLK = XT * H * B;  // 2560 fused blocks

static constexpr size_t PARAMS_OFF = 0;

typedef float f32x2 __attribute__((ext_vector_type(2)));
typedef float f32x4 __attribute__((ext_vector_type(4)));

// Alignment-safe paired load (global: dwordx2; LDS: ds_read2_b32)
__device__ __forceinline__ f32x2 ld2(const float* p) {
    f32x2 v;
    __builtin_memcpy(&v, p, sizeof(f32x2));
    return v;
}

// ---------------------------------------------------------------------------
// Setup: per (b, src view i=1..4) compute proj = M_i @ inv(M_0) -> 12 floats
// ---------------------------------------------------------------------------
__global__ void setup_proj_kernel(const float* __restrict__ pm, float* __restrict__ params) {
    int b = threadIdx.x;
    if (b >= B) return;

    float M[V][16];
    for (int v = 0; v < V; ++v) {
        const float* E  = pm + ((size_t)(b * V + v) * 2 + 0) * 16;
        const float* Km = pm + ((size_t)(b * V + v) * 2 + 1) * 16;
        for (int r = 0; r < 3; ++r)
            for (int c = 0; c < 4; ++c) {
                float s = 0.f;
                for (int k = 0; k < 3; ++k) s += Km[r * 4 + k] * E[k * 4 + c];
                M[v][r * 4 + c] = s;
            }
        for (int c = 0; c < 4; ++c) M[v][12 + c] = E[12 + c];
    }

    float A[9], bb[3];
    for (int r = 0; r < 3; ++r) {
        for (int c = 0; c < 3; ++c) A[r * 3 + c] = M[0][r * 4 + c];
        bb[r] = M[0][r * 4 + 3];
    }
    float det = A[0] * (A[4] * A[8] - A[5] * A[7])
              - A[1] * (A[3] * A[8] - A[5] * A[6])
              + A[2] * (A[3] * A[7] - A[4] * A[6]);
    float id = 1.f / det;
    float Ai[9];
    Ai[0] = (A[4] * A[8] - A[5] * A[7]) * id;
    Ai[1] = (A[2] * A[7] - A[1] * A[8]) * id;
    Ai[2] = (A[1] * A[5] - A[2] * A[4]) * id;
    Ai[3] = (A[5] * A[6] - A[3] * A[8]) * id;
    Ai[4] = (A[0] * A[8] - A[2] * A[6]) * id;
    Ai[5] = (A[2] * A[3] - A[0] * A[5]) * id;
    Ai[6] = (A[3] * A[7] - A[4] * A[6]) * id;
    Ai[7] = (A[1] * A[6] - A[0] * A[7]) * id;
    Ai[8] = (A[0] * A[4] - A[1] * A[3]) * id;
    float bi[3];
    for (int r = 0; r < 3; ++r)
        bi[r] = -(Ai[r * 3 + 0] * bb[0] + Ai[r * 3 + 1] * bb[1] + Ai[r * 3 + 2] * bb[2]);

    float Minv[16];
    for (int r = 0; r < 3; ++r) {
        for (int c = 0; c < 3; ++c) Minv[r * 4 + c] = Ai[r * 3 + c];
        Minv[r * 4 + 3] = bi[r];
    }
    Minv[12] = 0.f; Minv[13] = 0.f; Minv[14] = 0.f; Minv[15] = 1.f;

    for (int v = 1; v < V; ++v) {
        float* dst = params + (size_t)(b * (V - 1) + (v - 1)) * 12;
        for (int r = 0; r < 3; ++r)
            for (int c = 0; c < 4; ++c) {
                float s = 0.f;
                for (int k = 0; k < 4; ++k) s += M[v][r * 4 + k] * Minv[k * 4 + c];
                dst[r * 4 + c] = s;
            }
    }
}

// ---------------------------------------------------------------------------
// Fused kernel v9 = v8 design at NATURAL register allocation.
// r8's 782us was pure forced-spill: __launch_bounds__(256,5) capped VGPR at
// 48 -> R[4]/weight arrays went to scratch -> 2.7 GB of scratch traffic
// (FETCH 1.17 GB, WRITE 1.58 GB). The design itself was never tested.
// v9 changes exactly one thing vs v8: plain __launch_bounds__(256).
// Expected natural VGPR ~80-96 -> with 15.9 KB LDS, ~5 blocks/CU (20
// waves/CU), ~1.7x r5's residency, with staging latency hidden by R[4].
//  (1) 1 channel per phase, stage[NG][960] (15.6 KB LDS),
//  (2) register double-buffer R[4]: holds ch n+1 while gathering ch n,
//  (3) fully unrolled 8-phase loop (rf[ch] statically indexed, rule #20),
//  (4) no barriers in the loop (stage[g] wave-private, same-wave DS in-order),
//  (5) paired ds_read2 gathers,
//  (6) fast test (unsigned)o0<=638; compact cold fallback recomputes rows.
// ---------------------------------------------------------------------------
__global__ __launch_bounds__(256) void fused_kernel(
    const float* __restrict__ depth_values,   // (B,1,H,W)
    const float* __restrict__ features,       // (V,B,C,H,W)
    const float* __restrict__ depth_interval, // (B,1,H,W)
    const float* __restrict__ view_weights,   // (B,V-1,H,W)
    const float* __restrict__ params,         // (B,V-1,12)
    float* __restrict__ out)                  // (B,C*CN,H,W)
{
    const int tid = threadIdx.x;
    const int p   = tid & 63;
    const int g   = tid >> 6;

    // row-sharing XCD swizzle (bijective)
    const int d   = blockIdx.x;
    const int u   = d >> 3;             // 0..319
    const int r8  = d & 7;
    const int xt  = u % XT;
    const int rid = r8 * 64 + u / XT;   // 0..511
    const int y   = rid & (H - 1);
    const int b   = rid >> 8;

    const int x   = xt * 64 + p;
    const int pix = y * W + x;

    __shared__ float sp4[48];            // 4 views x 12 params
    __shared__ float stage[NG][960];     // per-group: 1ch x 3 rows x 320 (15.6 KB total)
    float* const sredp = &stage[0][0];   // aliased post-gather: [NG][CN][64]
    float* const simp  = &stage[0][0] + 1024;  // aliased post-gather: [CN][64]

    if (tid < 48) sp4[tid] = params[(size_t)b * 48 + tid];
    __syncthreads();

    const float invd = 1.f / depth_values[(size_t)b * HW + pix];
    const float itv  = depth_interval[(size_t)b * HW + pix];
    const float low  = invd - (CN * 0.5f) * itv;
    const float step = (CN * itv) / (float)(CN - 1);
    float dep[CN];
#pragma unroll
    for (int k = 0; k < CN; ++k) dep[k] = 1.f / (low + (float)k * step);

    // prefetch all 4 view weights (off the per-view critical chain)
    float vws[V - 1];
#pragma unroll
    for (int i = 0; i < V - 1; ++i)
        vws[i] = view_weights[((size_t)b * (V - 1) + i) * HW + pix];
    float wsum = 1e-5f;
#pragma unroll
    for (int i = 0; i < V - 1; ++i) wsum += vws[i];

    // this group's reference channels: read once -> NT load
    const float* refp = features + ((size_t)b * C + g * CG) * HW + pix;
    float rf[CG];
#pragma unroll
    for (int c = 0; c < CG; ++c) rf[c] = __builtin_nontemporal_load(refp + (size_t)c * HW);

    // per-lane staging offsets: slot = it*64+p covers 240 f32x4 = 960 floats
    // = 3 rows x 320 of ONE channel. Valid: slot<240 <=> it<3 || p<48.
    int soff[4];
#pragma unroll
    for (int it = 0; it < 4; ++it) {
        const int f   = (it * 64 + p) * 4;
        const int j   = (f >= 640) ? 2 : ((f >= 320) ? 1 : 0);
        const int col = f - j * 320;
        const int row = min(max(y - 1 + j, 0), H - 1);
        soff[it] = row * W + col;
    }

    // view iv source base for this group's channels; +VSTRIDE per view
    const size_t VSTRIDE = (size_t)B * C * HW;
    const float* src = features + ((size_t)(B + b) * C + g * CG) * HW;  // view 0 (iv=0)

    const float fx = (float)x, fy = (float)y;
    float volsum[CN] = {0.f, 0.f, 0.f, 0.f};

    // prime the register buffer with view0 ch0
    f32x4 R[4];
#pragma unroll
    for (int it = 0; it < 4; ++it)
        if (it < 3 || p < 48) R[it] = *(const f32x4*)(src + soff[it]);

    for (int iv = 0; iv < V - 1; ++iv, src += VSTRIDE) {
        const float* spv = &sp4[iv * 12];
        const float rx = spv[0] * fx + spv[1] * fy + spv[2];
        const float ry = spv[4] * fx + spv[5] * fy + spv[6];
        const float rz = spv[8] * fx + spv[9] * fy + spv[10];
        const float tx = spv[3], ty = spv[7], tz = spv[11];

        const float scale = vws[iv] * (1.f / (float)C);

        int   o0[CN];
        float wA0[CN], wB0[CN], wA1[CN], wB1[CN];
#pragma unroll
        for (int k = 0; k < CN; ++k) {
            const float dd = dep[k];
            const float px = rx * dd + tx;
            const float py = ry * dd + ty;
            const float pz = rz * dd + tz;
            const float iz = 1.f / pz;
            const float gx = px * iz;
            const float gy = py * iz;

            const float x0f = floorf(gx), y0f = floorf(gy);
            const float wx1 = gx - x0f, wy1 = gy - y0f;
            const float wx0 = 1.f - wx1, wy0 = 1.f - wy1;
            const int x0 = (int)x0f, y0 = (int)y0f;
            const int x1 = x0 + 1, y1 = y0 + 1;

            const bool vx0 = (x0 >= 0) && (x0 <= W - 1);
            const bool vx1 = (x1 >= 0) && (x1 <= W - 1);
            const bool vy0 = (y0 >= 0) && (y0 <= H - 1);
            const bool vy1 = (y1 >= 0) && (y1 <= H - 1);

            const int bx = min(max(x0, 0), W - 2);
            const int s  = x0 - bx;   // {-1, 0, 1} (else all weights 0)

            const float w00 = wx0 * wy0 * ((vx0 && vy0) ? scale : 0.f);
            const float w10 = wx1 * wy0 * ((vx1 && vy0) ? scale : 0.f);
            const float w01 = wx0 * wy1 * ((vx0 && vy1) ? scale : 0.f);
            const float w11 = wx1 * wy1 * ((vx1 && vy1) ? scale : 0.f);

            wA0[k] = (s == 0) ? w00 : ((s == -1) ? w10 : 0.f);
            wB0[k] = (s == 0) ? w10 : ((s == 1) ? w00 : 0.f);
            wA1[k] = (s == 0) ? w01 : ((s == -1) ? w11 : 0.f);
            wB1[k] = (s == 0) ? w11 : ((s == 1) ? w01 : 0.f);

            // staged-buffer offset; valid fast iff y0 in {y-1, y} <=> o0<=638
            o0[k] = (y0 - y + 1) * 320 + bx;
        }

        bool okrow = true;
#pragma unroll
        for (int k = 0; k < CN; ++k)
            okrow = okrow && ((unsigned)o0[k] <= 638u);

        if (__all(okrow)) {
            // 8 phases, fully unrolled (rf[ch] static). Per phase:
            // commit R (ch) -> LDS, prefetch ch+1 -> R, gather ch from LDS.
#pragma unroll
            for (int ch = 0; ch < CG; ++ch) {
                // commit staged regs (same-wave DS in-order: the previous
                // phase's ds_reads retire before these writes land)
#pragma unroll
                for (int it = 0; it < 4; ++it)
                    if (it < 3 || p < 48)
                        *(f32x4*)&stage[g][(it * 64 + p) * 4] = R[it];

                // issue-early prefetch of the next channel / next view's ch0
                const bool more = (ch < CG - 1) || (iv < V - 2);
                if (more) {
                    const float* nsrc = (ch < CG - 1) ? src + (size_t)(ch + 1) * HW
                                                      : src + VSTRIDE;
#pragma unroll
                    for (int it = 0; it < 4; ++it)
                        if (it < 3 || p < 48) R[it] = *(const f32x4*)(nsrc + soff[it]);
                }

                // gather this channel's 4 depths (paired ds_read2)
                const float rfc = rf[ch];
                const float* L = &stage[g][0];
#pragma unroll
                for (int k = 0; k < CN; ++k) {
                    const f32x2 a  = ld2(L + o0[k]);
                    const f32x2 b2 = ld2(L + o0[k] + 320);
                    float t = wA0[k] * a.x;
                    t = fmaf(wB0[k], a.y, t);
                    t = fmaf(wA1[k], b2.x, t);
                    t = fmaf(wB1[k], b2.y, t);
                    volsum[k] = fmaf(rfc, t, volsum[k]);
                }
            }
        } else {
            // GENERIC fallback (cold): compact global gather; recompute rows.
#pragma unroll 1
            for (int k = 0; k < CN; ++k) {
                const float dd = dep[k];
                const float gy = (ry * dd + ty) / (rz * dd + tz);
                const int   y0 = (int)floorf(gy);
                const int  cy0 = min(max(y0,     0), H - 1);
                const int  cy1 = min(max(y0 + 1, 0), H - 1);
                const int   bx = o0[k] - (y0 - y + 1) * 320;   // recover bx
                const int  ib0 = cy0 * W + bx;
                const int  ib1 = cy1 * W + bx;
#pragma unroll 1
                for (int c = 0; c < CG; ++c) {
                    const float* fc  = src + (size_t)c * HW;
                    const f32x2 a   = ld2(fc + ib0);
                    const f32x2 bb2 = ld2(fc + ib1);
                    float t = wA0[k] * a.x;
                    t = fmaf(wB0[k], a.y, t);
                    t = fmaf(wA1[k], bb2.x, t);
                    t = fmaf(wB1[k], bb2.y, t);
                    volsum[k] = fmaf(rf[c], t, volsum[k]);
                }
            }
            // re-prime the register buffer for the next view
            if (iv < V - 2) {
#pragma unroll
                for (int it = 0; it < 4; ++it)
                    if (it < 3 || p < 48) R[it] = *(const f32x4*)(src + VSTRIDE + soff[it]);
            }
        }
    }

    // cross-group reduce + normalize; sred/sim alias the (now dead) stage buf.
    __syncthreads();
#pragma unroll
    for (int k = 0; k < CN; ++k) sredp[(g * CN + k) * 64 + p] = volsum[k];
    __syncthreads();

    {
        const int k = g;   // NG == CN: group g owns depth k = g
        const float s = sredp[(0 * CN + k) * 64 + p] + sredp[(1 * CN + k) * 64 + p]
                      + sredp[(2 * CN + k) * 64 + p] + sredp[(3 * CN + k) * 64 + p];
        simp[k * 64 + p] = s * (1.f / wsum);
    }
    __syncthreads();

    // broadcast-write 128 planes x 64 px with regular cached stores.
    {
        const int quad = tid & 15;
        const int pc   = tid >> 4;
        float* op = out + (size_t)b * C * CN * HW + y * W + xt * 64 + quad * 4;
#pragma unroll
        for (int j = 0; j < 8; ++j) {
            const int plane = pc * 8 + j;          // 0..127, each exactly once
            const int k     = plane & 3;
            const f32x4 v   = *(const f32x4*)&simp[k * 64 + quad * 4];
            *(f32x4*)(op + (size_t)plane * HW) = v;
        }
    }
}

extern "C" void kernel_launch(void* const* d_in, const int* in_sizes, int n_in,
                              void* d_out, int out_size, void* d_ws, size_t ws_size,
                              hipStream_t stream) {
    const float* depth_values   = (const float*)d_in[0];
    const float* features       = (const float*)d_in[1];
    const float* proj_matrices  = (const float*)d_in[2];
    const float* depth_interval = (const float*)d_in[3];
    const float* view_weights   = (const float*)d_in[7];
    float* out    = (float*)d_out;
    float* params = (float*)d_ws + PARAMS_OFF;    // 96 floats

    setup_proj_kernel<<<1, B, 0, stream>>>(proj_matrices, params);

    fused_kernel<<<NBLK, 256, 0, stream>>>(depth_values, features, depth_interval,
                                           view_weights, params, out);
}

// Round 10
// 270.394 us; speedup vs baseline: 3.3391x; 1.0657x over previous
//
#include <hip/hip_runtime.h>

// Problem constants (fixed by setup_inputs)
static constexpr int V  = 5;
static constexpr int B  = 2;
static constexpr int C  = 32;
static constexpr int H  = 256;
static constexpr int W  = 320;
static constexpr int CN = 4;
static constexpr int HW = H * W;
static constexpr int CG = 8;   // channels per group (per wave)
static constexpr int NG = 4;   // groups per block
static constexpr int XT = W / 64;        // 5 x-tiles
static constexpr int NBLK = XT * H * B;  // 2560 fused blocks

static constexpr size_t PARAMS_OFF = 0;

typedef float f32x2 __attribute__((ext_vector_type(2)));
typedef float f32x4 __attribute__((ext_vector_type(4)));

// Alignment-safe paired load (global: dwordx2; LDS: ds_read2_b32)
__device__ __forceinline__ f32x2 ld2(const float* p) {
    f32x2 v;
    __builtin_memcpy(&v, p, sizeof(f32x2));
    return v;
}

// ---------------------------------------------------------------------------
// Setup: per (b, src view i=1..4) compute proj = M_i @ inv(M_0) -> 12 floats
// ---------------------------------------------------------------------------
__global__ void setup_proj_kernel(const float* __restrict__ pm, float* __restrict__ params) {
    int b = threadIdx.x;
    if (b >= B) return;

    float M[V][16];
    for (int v = 0; v < V; ++v) {
        const float* E  = pm + ((size_t)(b * V + v) * 2 + 0) * 16;
        const float* Km = pm + ((size_t)(b * V + v) * 2 + 1) * 16;
        for (int r = 0; r < 3; ++r)
            for (int c = 0; c < 4; ++c) {
                float s = 0.f;
                for (int k = 0; k < 3; ++k) s += Km[r * 4 + k] * E[k * 4 + c];
                M[v][r * 4 + c] = s;
            }
        for (int c = 0; c < 4; ++c) M[v][12 + c] = E[12 + c];
    }

    float A[9], bb[3];
    for (int r = 0; r < 3; ++r) {
        for (int c = 0; c < 3; ++c) A[r * 3 + c] = M[0][r * 4 + c];
        bb[r] = M[0][r * 4 + 3];
    }
    float det = A[0] * (A[4] * A[8] - A[5] * A[7])
              - A[1] * (A[3] * A[8] - A[5] * A[6])
              + A[2] * (A[3] * A[7] - A[4] * A[6]);
    float id = 1.f / det;
    float Ai[9];
    Ai[0] = (A[4] * A[8] - A[5] * A[7]) * id;
    Ai[1] = (A[2] * A[7] - A[1] * A[8]) * id;
    Ai[2] = (A[1] * A[5] - A[2] * A[4]) * id;
    Ai[3] = (A[5] * A[6] - A[3] * A[8]) * id;
    Ai[4] = (A[0] * A[8] - A[2] * A[6]) * id;
    Ai[5] = (A[2] * A[3] - A[0] * A[5]) * id;
    Ai[6] = (A[3] * A[7] - A[4] * A[6]) * id;
    Ai[7] = (A[1] * A[6] - A[0] * A[7]) * id;
    Ai[8] = (A[0] * A[4] - A[1] * A[3]) * id;
    float bi[3];
    for (int r = 0; r < 3; ++r)
        bi[r] = -(Ai[r * 3 + 0] * bb[0] + Ai[r * 3 + 1] * bb[1] + Ai[r * 3 + 2] * bb[2]);

    float Minv[16];
    for (int r = 0; r < 3; ++r) {
        for (int c = 0; c < 3; ++c) Minv[r * 4 + c] = Ai[r * 3 + c];
        Minv[r * 4 + 3] = bi[r];
    }
    Minv[12] = 0.f; Minv[13] = 0.f; Minv[14] = 0.f; Minv[15] = 1.f;

    for (int v = 1; v < V; ++v) {
        float* dst = params + (size_t)(b * (V - 1) + (v - 1)) * 12;
        for (int r = 0; r < 3; ++r)
            for (int c = 0; c < 4; ++c) {
                float s = 0.f;
                for (int k = 0; k < 4; ++k) s += M[v][r * 4 + k] * Minv[k * 4 + c];
                dst[r * 4 + c] = s;
            }
    }
}

// ---------------------------------------------------------------------------
// Fused kernel v10: DUAL-PIPE hybrid gather.
// Evidence (r2/r5/r9): time ~143-148us invariant to occupancy (22-38%) and
// to gather engine. r2 saturates the TA/L1 pipe (scattered global ld2,
// ~130us); r5/r9 saturate the LDS pipe (ds_read2 gather + staging writes,
// ~120us incl. conflicts). The pipes are INDEPENDENT -> run both at once:
//   per wave, channels 0-3 via LDS row staging, channels 4-7 via direct
//   global scattered ld2, interleaved per phase so each engine's latency
//   hides under the other's throughput work.
// Register discipline (r7/r9 lessons): no pointer arrays; one stage set
// Rs[4] + one global batch GA/GB[4] live per phase (die in-phase); global
// row addresses from o0[k] + scalar row bases via selects (rule #20);
// phases statically unrolled so rf[] is static. No barriers in the loop
// (stage[g] is wave-private; same-wave DS ops are in-order).
// ---------------------------------------------------------------------------
__global__ __launch_bounds__(256) void fused_kernel(
    const float* __restrict__ depth_values,   // (B,1,H,W)
    const float* __restrict__ features,       // (V,B,C,H,W)
    const float* __restrict__ depth_interval, // (B,1,H,W)
    const float* __restrict__ view_weights,   // (B,V-1,H,W)
    const float* __restrict__ params,         // (B,V-1,12)
    float* __restrict__ out)                  // (B,C*CN,H,W)
{
    const int tid = threadIdx.x;
    const int p   = tid & 63;
    const int g   = tid >> 6;

    // row-sharing XCD swizzle (bijective)
    const int d   = blockIdx.x;
    const int u   = d >> 3;             // 0..319
    const int r8  = d & 7;
    const int xt  = u % XT;
    const int rid = r8 * 64 + u / XT;   // 0..511
    const int y   = rid & (H - 1);
    const int b   = rid >> 8;

    const int x   = xt * 64 + p;
    const int pix = y * W + x;

    __shared__ float sp4[48];            // 4 views x 12 params
    __shared__ float stage[NG][960];     // per-group: 1ch x 3 rows x 320 (15.6 KB)
    float* const sredp = &stage[0][0];   // aliased post-gather: [NG][CN][64]
    float* const simp  = &stage[0][0] + 1024;  // aliased post-gather: [CN][64]

    if (tid < 48) sp4[tid] = params[(size_t)b * 48 + tid];
    __syncthreads();

    const float invd = 1.f / depth_values[(size_t)b * HW + pix];
    const float itv  = depth_interval[(size_t)b * HW + pix];
    const float low  = invd - (CN * 0.5f) * itv;
    const float step = (CN * itv) / (float)(CN - 1);
    float dep[CN];
#pragma unroll
    for (int k = 0; k < CN; ++k) dep[k] = 1.f / (low + (float)k * step);

    // prefetch all 4 view weights (off the per-view critical chain)
    float vws[V - 1];
#pragma unroll
    for (int i = 0; i < V - 1; ++i)
        vws[i] = view_weights[((size_t)b * (V - 1) + i) * HW + pix];
    float wsum = 1e-5f;
#pragma unroll
    for (int i = 0; i < V - 1; ++i) wsum += vws[i];

    // this group's reference channels: read once -> NT load
    const float* refp = features + ((size_t)b * C + g * CG) * HW + pix;
    float rf[CG];
#pragma unroll
    for (int c = 0; c < CG; ++c) rf[c] = __builtin_nontemporal_load(refp + (size_t)c * HW);

    // per-lane staging offsets: slot = it*64+p covers 240 f32x4 = 960 floats
    // = 3 rows x 320 of ONE channel. Valid: slot<240 <=> it<3 || p<48.
    int soff[4];
#pragma unroll
    for (int it = 0; it < 4; ++it) {
        const int f   = (it * 64 + p) * 4;
        const int j   = (f >= 640) ? 2 : ((f >= 320) ? 1 : 0);
        const int col = f - j * 320;
        const int row = min(max(y - 1 + j, 0), H - 1);
        soff[it] = row * W + col;
    }

    // scalar row bases for the global-gather half (clamped)
    const int rbm = max(y - 1, 0) * W;      // row y-1
    const int rb0 = y * W;                  // row y
    const int rbp = min(y + 1, H - 1) * W;  // row y+1

    const size_t VSTRIDE = (size_t)B * C * HW;
    const float* src = features + ((size_t)(B + b) * C + g * CG) * HW;  // view iv=0

    const float fx = (float)x, fy = (float)y;
    float volsum[CN] = {0.f, 0.f, 0.f, 0.f};

    for (int iv = 0; iv < V - 1; ++iv, src += VSTRIDE) {
        const float* spv = &sp4[iv * 12];
        const float rx = spv[0] * fx + spv[1] * fy + spv[2];
        const float ry = spv[4] * fx + spv[5] * fy + spv[6];
        const float rz = spv[8] * fx + spv[9] * fy + spv[10];
        const float tx = spv[3], ty = spv[7], tz = spv[11];

        const float scale = vws[iv] * (1.f / (float)C);

        int   o0[CN];
        float wA0[CN], wB0[CN], wA1[CN], wB1[CN];
#pragma unroll
        for (int k = 0; k < CN; ++k) {
            const float dd = dep[k];
            const float px = rx * dd + tx;
            const float py = ry * dd + ty;
            const float pz = rz * dd + tz;
            const float iz = 1.f / pz;
            const float gx = px * iz;
            const float gy = py * iz;

            const float x0f = floorf(gx), y0f = floorf(gy);
            const float wx1 = gx - x0f, wy1 = gy - y0f;
            const float wx0 = 1.f - wx1, wy0 = 1.f - wy1;
            const int x0 = (int)x0f, y0 = (int)y0f;
            const int x1 = x0 + 1, y1 = y0 + 1;

            const bool vx0 = (x0 >= 0) && (x0 <= W - 1);
            const bool vx1 = (x1 >= 0) && (x1 <= W - 1);
            const bool vy0 = (y0 >= 0) && (y0 <= H - 1);
            const bool vy1 = (y1 >= 0) && (y1 <= H - 1);

            const int bx = min(max(x0, 0), W - 2);
            const int s  = x0 - bx;   // {-1, 0, 1} (else all weights 0)

            const float w00 = wx0 * wy0 * ((vx0 && vy0) ? scale : 0.f);
            const float w10 = wx1 * wy0 * ((vx1 && vy0) ? scale : 0.f);
            const float w01 = wx0 * wy1 * ((vx0 && vy1) ? scale : 0.f);
            const float w11 = wx1 * wy1 * ((vx1 && vy1) ? scale : 0.f);

            wA0[k] = (s == 0) ? w00 : ((s == -1) ? w10 : 0.f);
            wB0[k] = (s == 0) ? w10 : ((s == 1) ? w00 : 0.f);
            wA1[k] = (s == 0) ? w01 : ((s == -1) ? w11 : 0.f);
            wB1[k] = (s == 0) ? w11 : ((s == 1) ? w01 : 0.f);

            // staged-buffer offset; fast iff y0 in {y-1, y} <=> 0<=o0<=638
            o0[k] = (y0 - y + 1) * 320 + bx;
        }

        bool okrow = true;
#pragma unroll
        for (int k = 0; k < CN; ++k)
            okrow = okrow && ((unsigned)o0[k] <= 638u);

        if (__all(okrow)) {
            // global-gather addresses for the direct half (derived from o0;
            // selects only, no runtime-indexed arrays)
            int ga0[CN], ga1[CN];
#pragma unroll
            for (int k = 0; k < CN; ++k) {
                const bool j1  = o0[k] >= 320;
                const int  col = o0[k] - (j1 ? 320 : 0);
                ga0[k] = (j1 ? rb0 : rbm) + col;   // bilinear row 0 (clamped)
                ga1[k] = (j1 ? rbp : rb0) + col;   // bilinear row 1 (clamped)
            }

            // 4 phases: LDS channel q  +  global channel q+4
#pragma unroll
            for (int q = 0; q < 4; ++q) {
                // (1) issue stage loads for LDS channel q
                const float* sc = src + (size_t)q * HW;
                f32x4 Rs0, Rs1, Rs2, Rs3;
                Rs0 = *(const f32x4*)(sc + soff[0]);
                Rs1 = *(const f32x4*)(sc + soff[1]);
                Rs2 = *(const f32x4*)(sc + soff[2]);
                if (p < 48) Rs3 = *(const f32x4*)(sc + soff[3]);

                // (2) issue global scattered batch for channel q+4
                const float* gc = src + (size_t)(q + 4) * HW;
                f32x2 GA[CN], GB[CN];
#pragma unroll
                for (int k = 0; k < CN; ++k) {
                    GA[k] = ld2(gc + ga0[k]);
                    GB[k] = ld2(gc + ga1[k]);
                }

                // (3) commit stage to LDS (waits only on Rs*)
                *(f32x4*)&stage[g][(0 * 64 + p) * 4] = Rs0;
                *(f32x4*)&stage[g][(1 * 64 + p) * 4] = Rs1;
                *(f32x4*)&stage[g][(2 * 64 + p) * 4] = Rs2;
                if (p < 48) *(f32x4*)&stage[g][(3 * 64 + p) * 4] = Rs3;

                // (4) gather LDS channel q (same-wave DS in-order)
                {
                    const float rfc = rf[q];
                    const float* L = &stage[g][0];
#pragma unroll
                    for (int k = 0; k < CN; ++k) {
                        const f32x2 a  = ld2(L + o0[k]);
                        const f32x2 b2 = ld2(L + o0[k] + 320);
                        float t = wA0[k] * a.x;
                        t = fmaf(wB0[k], a.y, t);
                        t = fmaf(wA1[k], b2.x, t);
                        t = fmaf(wB1[k], b2.y, t);
                        volsum[k] = fmaf(rfc, t, volsum[k]);
                    }
                }

                // (5) consume the global batch for channel q+4
                {
                    const float rfc = rf[q + 4];
#pragma unroll
                    for (int k = 0; k < CN; ++k) {
                        float t = wA0[k] * GA[k].x;
                        t = fmaf(wB0[k], GA[k].y, t);
                        t = fmaf(wA1[k], GB[k].x, t);
                        t = fmaf(wB1[k], GB[k].y, t);
                        volsum[k] = fmaf(rfc, t, volsum[k]);
                    }
                }
            }
        } else {
            // GENERIC fallback (cold): compact global gather; recompute rows.
#pragma unroll 1
            for (int k = 0; k < CN; ++k) {
                const float dd = dep[k];
                const float gy = (ry * dd + ty) / (rz * dd + tz);
                const int   y0 = (int)floorf(gy);
                const int  cy0 = min(max(y0,     0), H - 1);
                const int  cy1 = min(max(y0 + 1, 0), H - 1);
                const int   bx = o0[k] - (y0 - y + 1) * 320;   // recover bx
                const int  ib0 = cy0 * W + bx;
                const int  ib1 = cy1 * W + bx;
#pragma unroll 1
                for (int c = 0; c < CG; ++c) {
                    const float* fc  = src + (size_t)c * HW;
                    const f32x2 a   = ld2(fc + ib0);
                    const f32x2 bb2 = ld2(fc + ib1);
                    float t = wA0[k] * a.x;
                    t = fmaf(wB0[k], a.y, t);
                    t = fmaf(wA1[k], bb2.x, t);
                    t = fmaf(wB1[k], bb2.y, t);
                    volsum[k] = fmaf(rf[c], t, volsum[k]);
                }
            }
        }
    }

    // cross-group reduce + normalize; sred/sim alias the (now dead) stage buf.
    __syncthreads();
#pragma unroll
    for (int k = 0; k < CN; ++k) sredp[(g * CN + k) * 64 + p] = volsum[k];
    __syncthreads();

    {
        const int k = g;   // NG == CN: group g owns depth k = g
        const float s = sredp[(0 * CN + k) * 64 + p] + sredp[(1 * CN + k) * 64 + p]
                      + sredp[(2 * CN + k) * 64 + p] + sredp[(3 * CN + k) * 64 + p];
        simp[k * 64 + p] = s * (1.f / wsum);
    }
    __syncthreads();

    // broadcast-write 128 planes x 64 px with regular cached stores.
    {
        const int quad = tid & 15;
        const int pc   = tid >> 4;
        float* op = out + (size_t)b * C * CN * HW + y * W + xt * 64 + quad * 4;
#pragma unroll
        for (int j = 0; j < 8; ++j) {
            const int plane = pc * 8 + j;          // 0..127, each exactly once
            const int k     = plane & 3;
            const f32x4 v   = *(const f32x4*)&simp[k * 64 + quad * 4];
            *(f32x4*)(op + (size_t)plane * HW) = v;
        }
    }
}

extern "C" void kernel_launch(void* const* d_in, const int* in_sizes, int n_in,
                              void* d_out, int out_size, void* d_ws, size_t ws_size,
                              hipStream_t stream) {
    const float* depth_values   = (const float*)d_in[0];
    const float* features       = (const float*)d_in[1];
    const float* proj_matrices  = (const float*)d_in[2];
    const float* depth_interval = (const float*)d_in[3];
    const float* view_weights   = (const float*)d_in[7];
    float* out    = (float*)d_out;
    float* params = (float*)d_ws + PARAMS_OFF;    // 96 floats

    setup_proj_kernel<<<1, B, 0, stream>>>(proj_matrices, params);

    fused_kernel<<<NBLK, 256, 0, stream>>>(depth_values, features, depth_interval,
                                           view_weights, params, out);
}

// Round 11
// 267.727 us; speedup vs baseline: 3.3724x; 1.0100x over previous
//
#include <hip/hip_runtime.h>

// Problem constants (fixed by setup_inputs)
static constexpr int V  = 5;
static constexpr int B  = 2;
static constexpr int C  = 32;
static constexpr int H  = 256;
static constexpr int W  = 320;
static constexpr int CN = 4;
static constexpr int HW = H * W;
static constexpr int CG = 8;   // channels per group (per wave)
static constexpr int NG = 4;   // groups per block
static constexpr int XT = W / 64;        // 5 x-tiles
static constexpr int NBLK = XT * H * B;  // 2560 fused blocks

static constexpr size_t PARAMS_OFF = 0;

typedef float f32x2 __attribute__((ext_vector_type(2)));
typedef float f32x4 __attribute__((ext_vector_type(4)));

// Alignment-safe paired load (global: dwordx2; LDS: ds_read2_b32)
__device__ __forceinline__ f32x2 ld2(const float* p) {
    f32x2 v;
    __builtin_memcpy(&v, p, sizeof(f32x2));
    return v;
}

// ---------------------------------------------------------------------------
// Setup: per (b, src view i=1..4) compute proj = M_i @ inv(M_0) -> 12 floats
// ---------------------------------------------------------------------------
__global__ void setup_proj_kernel(const float* __restrict__ pm, float* __restrict__ params) {
    int b = threadIdx.x;
    if (b >= B) return;

    float M[V][16];
    for (int v = 0; v < V; ++v) {
        const float* E  = pm + ((size_t)(b * V + v) * 2 + 0) * 16;
        const float* Km = pm + ((size_t)(b * V + v) * 2 + 1) * 16;
        for (int r = 0; r < 3; ++r)
            for (int c = 0; c < 4; ++c) {
                float s = 0.f;
                for (int k = 0; k < 3; ++k) s += Km[r * 4 + k] * E[k * 4 + c];
                M[v][r * 4 + c] = s;
            }
        for (int c = 0; c < 4; ++c) M[v][12 + c] = E[12 + c];
    }

    float A[9], bb[3];
    for (int r = 0; r < 3; ++r) {
        for (int c = 0; c < 3; ++c) A[r * 3 + c] = M[0][r * 4 + c];
        bb[r] = M[0][r * 4 + 3];
    }
    float det = A[0] * (A[4] * A[8] - A[5] * A[7])
              - A[1] * (A[3] * A[8] - A[5] * A[6])
              + A[2] * (A[3] * A[7] - A[4] * A[6]);
    float id = 1.f / det;
    float Ai[9];
    Ai[0] = (A[4] * A[8] - A[5] * A[7]) * id;
    Ai[1] = (A[2] * A[7] - A[1] * A[8]) * id;
    Ai[2] = (A[1] * A[5] - A[2] * A[4]) * id;
    Ai[3] = (A[5] * A[6] - A[3] * A[8]) * id;
    Ai[4] = (A[0] * A[8] - A[2] * A[6]) * id;
    Ai[5] = (A[2] * A[3] - A[0] * A[5]) * id;
    Ai[6] = (A[3] * A[7] - A[4] * A[6]) * id;
    Ai[7] = (A[1] * A[6] - A[0] * A[7]) * id;
    Ai[8] = (A[0] * A[4] - A[1] * A[3]) * id;
    float bi[3];
    for (int r = 0; r < 3; ++r)
        bi[r] = -(Ai[r * 3 + 0] * bb[0] + Ai[r * 3 + 1] * bb[1] + Ai[r * 3 + 2] * bb[2]);

    float Minv[16];
    for (int r = 0; r < 3; ++r) {
        for (int c = 0; c < 3; ++c) Minv[r * 4 + c] = Ai[r * 3 + c];
        Minv[r * 4 + 3] = bi[r];
    }
    Minv[12] = 0.f; Minv[13] = 0.f; Minv[14] = 0.f; Minv[15] = 1.f;

    for (int v = 1; v < V; ++v) {
        float* dst = params + (size_t)(b * (V - 1) + (v - 1)) * 12;
        for (int r = 0; r < 3; ++r)
            for (int c = 0; c < 4; ++c) {
                float s = 0.f;
                for (int k = 0; k < 4; ++k) s += M[v][r * 4 + k] * Minv[k * 4 + c];
                dst[r * 4 + c] = s;
            }
    }
}

// ---------------------------------------------------------------------------
// Fused kernel v11 = v10 dual-pipe + one-phase-ahead stage prefetch.
// v10 (128us, conflicts halved) confirmed the dual-pipe mechanism, but the
// LDS half's chain [Rs global load -> vmcnt -> ds_write -> ds_read -> FMA]
// left the Rs latency exposed mid-phase (occupancy ~21% = ~1.7 waves/SIMD,
// no TLP cover; and r2/r5/r9/r10 proved occupancy 21-38% is non-binding ->
// the lever is ILP). v11: Rs for channel q+1 issues during phase q; next
// view's ch0 issues during phase 3 (soff[] is view-independent). By commit
// time the loads have a full phase (2 gathers + 40 FMA) in flight.
// Single stage buffer (same-wave DS in-order => WAR safe), LDS 15.6 KB.
// Cost: Rs (16 VGPR) lives across phases -> expect VGPR ~128-140.
// ---------------------------------------------------------------------------
__global__ __launch_bounds__(256) void fused_kernel(
    const float* __restrict__ depth_values,   // (B,1,H,W)
    const float* __restrict__ features,       // (V,B,C,H,W)
    const float* __restrict__ depth_interval, // (B,1,H,W)
    const float* __restrict__ view_weights,   // (B,V-1,H,W)
    const float* __restrict__ params,         // (B,V-1,12)
    float* __restrict__ out)                  // (B,C*CN,H,W)
{
    const int tid = threadIdx.x;
    const int p   = tid & 63;
    const int g   = tid >> 6;

    // row-sharing XCD swizzle (bijective)
    const int d   = blockIdx.x;
    const int u   = d >> 3;             // 0..319
    const int r8  = d & 7;
    const int xt  = u % XT;
    const int rid = r8 * 64 + u / XT;   // 0..511
    const int y   = rid & (H - 1);
    const int b   = rid >> 8;

    const int x   = xt * 64 + p;
    const int pix = y * W + x;

    __shared__ float sp4[48];            // 4 views x 12 params
    __shared__ float stage[NG][960];     // per-group: 1ch x 3 rows x 320 (15.6 KB)
    float* const sredp = &stage[0][0];   // aliased post-gather: [NG][CN][64]
    float* const simp  = &stage[0][0] + 1024;  // aliased post-gather: [CN][64]

    if (tid < 48) sp4[tid] = params[(size_t)b * 48 + tid];
    __syncthreads();

    const float invd = 1.f / depth_values[(size_t)b * HW + pix];
    const float itv  = depth_interval[(size_t)b * HW + pix];
    const float low  = invd - (CN * 0.5f) * itv;
    const float step = (CN * itv) / (float)(CN - 1);
    float dep[CN];
#pragma unroll
    for (int k = 0; k < CN; ++k) dep[k] = 1.f / (low + (float)k * step);

    // prefetch all 4 view weights (off the per-view critical chain)
    float vws[V - 1];
#pragma unroll
    for (int i = 0; i < V - 1; ++i)
        vws[i] = view_weights[((size_t)b * (V - 1) + i) * HW + pix];
    float wsum = 1e-5f;
#pragma unroll
    for (int i = 0; i < V - 1; ++i) wsum += vws[i];

    // this group's reference channels: read once -> NT load
    const float* refp = features + ((size_t)b * C + g * CG) * HW + pix;
    float rf[CG];
#pragma unroll
    for (int c = 0; c < CG; ++c) rf[c] = __builtin_nontemporal_load(refp + (size_t)c * HW);

    // per-lane staging offsets: slot = it*64+p covers 240 f32x4 = 960 floats
    // = 3 rows x 320 of ONE channel. Valid: slot<240 <=> it<3 || p<48.
    int soff[4];
#pragma unroll
    for (int it = 0; it < 4; ++it) {
        const int f   = (it * 64 + p) * 4;
        const int j   = (f >= 640) ? 2 : ((f >= 320) ? 1 : 0);
        const int col = f - j * 320;
        const int row = min(max(y - 1 + j, 0), H - 1);
        soff[it] = row * W + col;
    }

    // scalar row bases for the global-gather half (clamped)
    const int rbm = max(y - 1, 0) * W;      // row y-1
    const int rb0 = y * W;                  // row y
    const int rbp = min(y + 1, H - 1) * W;  // row y+1

    const size_t VSTRIDE = (size_t)B * C * HW;
    const float* src = features + ((size_t)(B + b) * C + g * CG) * HW;  // view iv=0

    const float fx = (float)x, fy = (float)y;
    float volsum[CN] = {0.f, 0.f, 0.f, 0.f};

    // prime staging registers with view0 ch0 (one phase ahead)
    f32x4 Rs0, Rs1, Rs2, Rs3;
    Rs0 = *(const f32x4*)(src + soff[0]);
    Rs1 = *(const f32x4*)(src + soff[1]);
    Rs2 = *(const f32x4*)(src + soff[2]);
    if (p < 48) Rs3 = *(const f32x4*)(src + soff[3]);

    for (int iv = 0; iv < V - 1; ++iv, src += VSTRIDE) {
        const float* spv = &sp4[iv * 12];
        const float rx = spv[0] * fx + spv[1] * fy + spv[2];
        const float ry = spv[4] * fx + spv[5] * fy + spv[6];
        const float rz = spv[8] * fx + spv[9] * fy + spv[10];
        const float tx = spv[3], ty = spv[7], tz = spv[11];

        const float scale = vws[iv] * (1.f / (float)C);

        int   o0[CN];
        float wA0[CN], wB0[CN], wA1[CN], wB1[CN];
#pragma unroll
        for (int k = 0; k < CN; ++k) {
            const float dd = dep[k];
            const float px = rx * dd + tx;
            const float py = ry * dd + ty;
            const float pz = rz * dd + tz;
            const float iz = 1.f / pz;
            const float gx = px * iz;
            const float gy = py * iz;

            const float x0f = floorf(gx), y0f = floorf(gy);
            const float wx1 = gx - x0f, wy1 = gy - y0f;
            const float wx0 = 1.f - wx1, wy0 = 1.f - wy1;
            const int x0 = (int)x0f, y0 = (int)y0f;
            const int x1 = x0 + 1, y1 = y0 + 1;

            const bool vx0 = (x0 >= 0) && (x0 <= W - 1);
            const bool vx1 = (x1 >= 0) && (x1 <= W - 1);
            const bool vy0 = (y0 >= 0) && (y0 <= H - 1);
            const bool vy1 = (y1 >= 0) && (y1 <= H - 1);

            const int bx = min(max(x0, 0), W - 2);
            const int s  = x0 - bx;   // {-1, 0, 1} (else all weights 0)

            const float w00 = wx0 * wy0 * ((vx0 && vy0) ? scale : 0.f);
            const float w10 = wx1 * wy0 * ((vx1 && vy0) ? scale : 0.f);
            const float w01 = wx0 * wy1 * ((vx0 && vy1) ? scale : 0.f);
            const float w11 = wx1 * wy1 * ((vx1 && vy1) ? scale : 0.f);

            wA0[k] = (s == 0) ? w00 : ((s == -1) ? w10 : 0.f);
            wB0[k] = (s == 0) ? w10 : ((s == 1) ? w00 : 0.f);
            wA1[k] = (s == 0) ? w01 : ((s == -1) ? w11 : 0.f);
            wB1[k] = (s == 0) ? w11 : ((s == 1) ? w01 : 0.f);

            // staged-buffer offset; fast iff y0 in {y-1, y} <=> 0<=o0<=638
            o0[k] = (y0 - y + 1) * 320 + bx;
        }

        bool okrow = true;
#pragma unroll
        for (int k = 0; k < CN; ++k)
            okrow = okrow && ((unsigned)o0[k] <= 638u);

        if (__all(okrow)) {
            // global-gather addresses for the direct half (derived from o0;
            // selects only, no runtime-indexed arrays)
            int ga0[CN], ga1[CN];
#pragma unroll
            for (int k = 0; k < CN; ++k) {
                const bool j1  = o0[k] >= 320;
                const int  col = o0[k] - (j1 ? 320 : 0);
                ga0[k] = (j1 ? rb0 : rbm) + col;   // bilinear row 0 (clamped)
                ga1[k] = (j1 ? rbp : rb0) + col;   // bilinear row 1 (clamped)
            }

            // 4 phases: LDS channel q (staged one phase ahead) + global ch q+4
#pragma unroll
            for (int q = 0; q < 4; ++q) {
                // (1) commit prefetched stage regs for channel q
                //     (vmcnt wait on Rs covered by previous phase's work)
                *(f32x4*)&stage[g][(0 * 64 + p) * 4] = Rs0;
                *(f32x4*)&stage[g][(1 * 64 + p) * 4] = Rs1;
                *(f32x4*)&stage[g][(2 * 64 + p) * 4] = Rs2;
                if (p < 48) *(f32x4*)&stage[g][(3 * 64 + p) * 4] = Rs3;

                // (2) issue NEXT stage loads: ch q+1, or next view's ch0
                const bool more = (q < 3) || (iv < V - 2);
                if (more) {
                    const float* ns = (q < 3) ? src + (size_t)(q + 1) * HW
                                              : src + VSTRIDE;
                    Rs0 = *(const f32x4*)(ns + soff[0]);
                    Rs1 = *(const f32x4*)(ns + soff[1]);
                    Rs2 = *(const f32x4*)(ns + soff[2]);
                    if (p < 48) Rs3 = *(const f32x4*)(ns + soff[3]);
                }

                // (3) issue global scattered batch for channel q+4
                const float* gc = src + (size_t)(q + 4) * HW;
                f32x2 GA[CN], GB[CN];
#pragma unroll
                for (int k = 0; k < CN; ++k) {
                    GA[k] = ld2(gc + ga0[k]);
                    GB[k] = ld2(gc + ga1[k]);
                }

                // (4) gather LDS channel q (same-wave DS in-order after commit)
                {
                    const float rfc = rf[q];
                    const float* L = &stage[g][0];
#pragma unroll
                    for (int k = 0; k < CN; ++k) {
                        const f32x2 a  = ld2(L + o0[k]);
                        const f32x2 b2 = ld2(L + o0[k] + 320);
                        float t = wA0[k] * a.x;
                        t = fmaf(wB0[k], a.y, t);
                        t = fmaf(wA1[k], b2.x, t);
                        t = fmaf(wB1[k], b2.y, t);
                        volsum[k] = fmaf(rfc, t, volsum[k]);
                    }
                }

                // (5) consume the global batch for channel q+4
                {
                    const float rfc = rf[q + 4];
#pragma unroll
                    for (int k = 0; k < CN; ++k) {
                        float t = wA0[k] * GA[k].x;
                        t = fmaf(wB0[k], GA[k].y, t);
                        t = fmaf(wA1[k], GB[k].x, t);
                        t = fmaf(wB1[k], GB[k].y, t);
                        volsum[k] = fmaf(rfc, t, volsum[k]);
                    }
                }
            }
        } else {
            // GENERIC fallback (cold): compact global gather; recompute rows.
#pragma unroll 1
            for (int k = 0; k < CN; ++k) {
                const float dd = dep[k];
                const float gy = (ry * dd + ty) / (rz * dd + tz);
                const int   y0 = (int)floorf(gy);
                const int  cy0 = min(max(y0,     0), H - 1);
                const int  cy1 = min(max(y0 + 1, 0), H - 1);
                const int   bx = o0[k] - (y0 - y + 1) * 320;   // recover bx
                const int  ib0 = cy0 * W + bx;
                const int  ib1 = cy1 * W + bx;
#pragma unroll 1
                for (int c = 0; c < CG; ++c) {
                    const float* fc  = src + (size_t)c * HW;
                    const f32x2 a   = ld2(fc + ib0);
                    const f32x2 bb2 = ld2(fc + ib1);
                    float t = wA0[k] * a.x;
                    t = fmaf(wB0[k], a.y, t);
                    t = fmaf(wA1[k], bb2.x, t);
                    t = fmaf(wB1[k], bb2.y, t);
                    volsum[k] = fmaf(rf[c], t, volsum[k]);
                }
            }
            // re-prime staging registers for the next view
            if (iv < V - 2) {
                const float* ns = src + VSTRIDE;
                Rs0 = *(const f32x4*)(ns + soff[0]);
                Rs1 = *(const f32x4*)(ns + soff[1]);
                Rs2 = *(const f32x4*)(ns + soff[2]);
                if (p < 48) Rs3 = *(const f32x4*)(ns + soff[3]);
            }
        }
    }

    // cross-group reduce + normalize; sred/sim alias the (now dead) stage buf.
    __syncthreads();
#pragma unroll
    for (int k = 0; k < CN; ++k) sredp[(g * CN + k) * 64 + p] = volsum[k];
    __syncthreads();

    {
        const int k = g;   // NG == CN: group g owns depth k = g
        const float s = sredp[(0 * CN + k) * 64 + p] + sredp[(1 * CN + k) * 64 + p]
                      + sredp[(2 * CN + k) * 64 + p] + sredp[(3 * CN + k) * 64 + p];
        simp[k * 64 + p] = s * (1.f / wsum);
    }
    __syncthreads();

    // broadcast-write 128 planes x 64 px with regular cached stores.
    {
        const int quad = tid & 15;
        const int pc   = tid >> 4;
        float* op = out + (size_t)b * C * CN * HW + y * W + xt * 64 + quad * 4;
#pragma unroll
        for (int j = 0; j < 8; ++j) {
            const int plane = pc * 8 + j;          // 0..127, each exactly once
            const int k     = plane & 3;
            const f32x4 v   = *(const f32x4*)&simp[k * 64 + quad * 4];
            *(f32x4*)(op + (size_t)plane * HW) = v;
        }
    }
}

extern "C" void kernel_launch(void* const* d_in, const int* in_sizes, int n_in,
                              void* d_out, int out_size, void* d_ws, size_t ws_size,
                              hipStream_t stream) {
    const float* depth_values   = (const float*)d_in[0];
    const float* features       = (const float*)d_in[1];
    const float* proj_matrices  = (const float*)d_in[2];
    const float* depth_interval = (const float*)d_in[3];
    const float* view_weights   = (const float*)d_in[7];
    float* out    = (float*)d_out;
    float* params = (float*)d_ws + PARAMS_OFF;    // 96 floats

    setup_proj_kernel<<<1, B, 0, stream>>>(proj_matrices, params);

    fused_kernel<<<NBLK, 256, 0, stream>>>(depth_values, features, depth_interval,
                                           view_weights, params, out);
}